// Round 16
// baseline (205.459 us; speedup 1.0000x reference)
//
#include <hip/hip_runtime.h>
#include <hip/hip_bf16.h>
#include <stdint.h>

#define S_LEN  2048
#define BATCH  2
#define DMODEL 2048
#define EQKV   3072
#define HQ     32
#define HKV    8
#define HD     64
#define MROWS  (BATCH * S_LEN)  // 4096

typedef unsigned short u16;
typedef __attribute__((ext_vector_type(8))) short bf16x8;
typedef __attribute__((ext_vector_type(4))) short bf16x4;
typedef __attribute__((ext_vector_type(4))) float f32x4;

__device__ __forceinline__ u16 f2bf(float f) {
  uint32_t x = __builtin_bit_cast(uint32_t, f);
  uint32_t r = x + 0x7fffu + ((x >> 16) & 1u);
  return (u16)(r >> 16);
}
__device__ __forceinline__ short f2bf_s(float f) {
  return __builtin_bit_cast(short, __float2bfloat16(f));
}
__device__ __forceinline__ float b2f(u16 u) {
  uint32_t x = ((uint32_t)u) << 16;
  return __builtin_bit_cast(float, x);
}
__device__ __forceinline__ float fexp2(float x) {
#if __has_builtin(__builtin_amdgcn_exp2f)
  return __builtin_amdgcn_exp2f(x);
#else
  return exp2f(x);
#endif
}

__device__ __forceinline__ void gld16(const void* g, void* l) {
  __builtin_amdgcn_global_load_lds(
      (const __attribute__((address_space(1))) void*)g,
      (__attribute__((address_space(3))) void*)l, 16, 0, 0);
}

// ---------------- cast fp32 -> bf16, region-split (uniform branch per block) ----------------
// blocks [0,2048): x; [2048,3584): w_qkv; [3584,4608): w_out.
// One thread = 2 consecutive 8-elem units (64B read, 32B write), no loop.
#define CAST_BLOCKS 4608
__global__ __launch_bounds__(256) void cast3(const float* __restrict__ xa, const float* __restrict__ xb,
                      const float* __restrict__ xc,
                      u16* __restrict__ oa, u16* __restrict__ ob, u16* __restrict__ oc) {
  const float* in;
  u16* out;
  int bid = blockIdx.x;
  if (bid < 2048)      { in = xa; out = oa; }
  else if (bid < 3584) { in = xb; out = ob; bid -= 2048; }
  else                 { in = xc; out = oc; bid -= 3584; }
  size_t u0 = ((size_t)bid * 256 + threadIdx.x) * 2;   // unit index (8 elems/unit)
#pragma unroll
  for (int k = 0; k < 2; ++k) {
    size_t j = u0 + k;
    const float4* p = (const float4*)(in + j * 8);
    float4 a = p[0], b = p[1];
    uint32_t w0 = (uint32_t)(u16)f2bf_s(a.x) | ((uint32_t)(u16)f2bf_s(a.y) << 16);
    uint32_t w1 = (uint32_t)(u16)f2bf_s(a.z) | ((uint32_t)(u16)f2bf_s(a.w) << 16);
    uint32_t w2 = (uint32_t)(u16)f2bf_s(b.x) | ((uint32_t)(u16)f2bf_s(b.y) << 16);
    uint32_t w3 = (uint32_t)(u16)f2bf_s(b.z) | ((uint32_t)(u16)f2bf_s(b.w) << 16);
    *(uint4*)(out + j * 8) = make_uint4(w0, w1, w2, w3);
  }
}

// ---------------- bf16 GEMM, C = A * B^T ----------------
// 128x128 tile, BK=64, 8 waves (2 row-halves x 4 col-quarters; 64x32 per wave).
// LDS [128 rows][8 x 16B units]; unit u of row r holds global k-unit u^(r&7),
// staged via global_load_lds (linear dest) with pre-swizzled SOURCE unit.
template<int OUT_BF16>
__global__ __launch_bounds__(512) void gemm_bt(const u16* __restrict__ A,
                                               const u16* __restrict__ Bm,
                                               void* __restrict__ Cv,
                                               int M, int N, int K, int nbx) {
  __shared__ u16 lA[128 * 64];
  __shared__ u16 lB[128 * 64];
  const int tid  = threadIdx.x;
  const int wave = tid >> 6;
  const int lane = tid & 63;

  const int nwg = gridDim.x;
  const int wg  = blockIdx.x;
  const int swz = (wg & 7) * (nwg >> 3) + (wg >> 3);
  const int brow = (swz % nbx) * 128;
  const int bcol = (swz / nbx) * 128;

  const int wr = (wave >> 2) * 64;   // row half
  const int wc = (wave & 3) * 32;    // col quarter
  const int fr = lane & 15;
  const int fq = lane >> 4;

  const int srow8 = lane >> 3;                    // row within 8-row chunk
  const int scol  = ((lane & 7) ^ srow8) * 8;     // pre-swizzled source k-unit

  f32x4 acc[4][2];
#pragma unroll
  for (int i = 0; i < 4; ++i)
#pragma unroll
    for (int j = 0; j < 2; ++j) acc[i][j] = (f32x4){0.f, 0.f, 0.f, 0.f};

  for (int k0 = 0; k0 < K; k0 += 64) {
    __syncthreads();
#pragma unroll
    for (int j = 0; j < 2; ++j) {
      int c = wave * 2 + j;                 // chunk id 0..15
      int r = c * 8 + srow8;
      gld16(A  + (size_t)(brow + r) * K + k0 + scol, (char*)lA + c * 1024);
      gld16(Bm + (size_t)(bcol + r) * K + k0 + scol, (char*)lB + c * 1024);
    }
    __syncthreads();

    bf16x8 af[2][4], bfr[2][2];
#pragma unroll
    for (int kc = 0; kc < 2; ++kc) {
#pragma unroll
      for (int i = 0; i < 4; ++i) {
        int row = wr + i * 16 + fr;
        af[kc][i] = *(const bf16x8*)&lA[row * 64 + (((kc * 4 + fq) ^ (row & 7)) << 3)];
      }
#pragma unroll
      for (int j = 0; j < 2; ++j) {
        int row = wc + j * 16 + fr;
        bfr[kc][j] = *(const bf16x8*)&lB[row * 64 + (((kc * 4 + fq) ^ (row & 7)) << 3)];
      }
    }
#pragma unroll
    for (int kc = 0; kc < 2; ++kc)
#pragma unroll
      for (int i = 0; i < 4; ++i)
#pragma unroll
        for (int j = 0; j < 2; ++j)
          acc[i][j] = __builtin_amdgcn_mfma_f32_16x16x32_bf16(af[kc][i], bfr[kc][j], acc[i][j], 0, 0, 0);
  }

#pragma unroll
  for (int i = 0; i < 4; ++i)
#pragma unroll
    for (int j = 0; j < 2; ++j)
#pragma unroll
      for (int v = 0; v < 4; ++v) {
        int row = brow + wr + i * 16 + fq * 4 + v;
        int col = bcol + wc + j * 16 + fr;
        float val = acc[i][j][v];
        if (OUT_BF16) ((u16*)Cv)[(size_t)row * N + col] = f2bf(val);
        else          ((float*)Cv)[(size_t)row * N + col] = val;
      }
}

// ---------------- fused prep: RMSNorm+RoPE (Q/K) and V transpose ----------------
// blocks [0, 40960): rmsrope — one wave per (b,s,head<40) row of 64.
//   Q rows additionally pre-scaled by log2(e)/8 (attn's fixed-max softmax scale).
//   Trig via revolution-space reduction + native __sinf/__cosf.
// blocks [40960, 41472): vtrans — V heads -> VT [b*8+kh][d=64][S=2048].
#define RMS_BLOCKS 40960
__global__ __launch_bounds__(256) void prep(const u16* __restrict__ qkv,
                                            u16* __restrict__ Qb,
                                            u16* __restrict__ Kb,
                                            u16* __restrict__ VTb,
                                            const float* __restrict__ qg,
                                            const float* __restrict__ kg) {
  __shared__ u16 T[64][68];
  if (blockIdx.x < RMS_BLOCKS) {
    int wid  = blockIdx.x * 4 + (threadIdx.x >> 6);
    int lane = threadIdx.x & 63;
    int head = wid % 40;
    int bs   = wid / 40;
    int s    = bs & (S_LEN - 1);
    int b    = bs >> 11;

    float v = b2f(qkv[(size_t)bs * EQKV + head * HD + lane]);
    float ss = v * v;
#pragma unroll
    for (int msk = 32; msk >= 1; msk >>= 1) ss += __shfl_xor(ss, msk);
    float norm = sqrtf(ss);
    float g = (head < 32) ? qg[lane] : kg[lane];
    float xv = v * (8.0f * g / fmaxf(norm, 1e-6f));
    float prt = __shfl_xor(xv, 32);
    int i = lane & 31;
    // freq in revolutions: exp(-i*ln(1e4)/32) / (2*pi)
    float freq_rev = __expf(-(float)i * 0.28782313662425572f) * 0.15915494309189535f;
    float tr = (float)s * freq_rev;
    tr -= floorf(tr);
    float ang = tr * 6.283185307179586f;
    float sn = __sinf(ang), cs = __cosf(ang);
    float res = (lane < 32) ? (xv * cs - prt * sn) : (prt * sn + xv * cs);
    if (head < 32) {
      res *= 0.18033688011112042f;   // fold log2(e)/8 into stored Q
      Qb[(((size_t)(b * HQ  + head     )) * S_LEN + s) * HD + lane] = f2bf(res);
    } else {
      Kb[(((size_t)(b * HKV + head - 32)) * S_LEN + s) * HD + lane] = f2bf(res);
    }
  } else {
    const int bid   = blockIdx.x - RMS_BLOCKS;   // 0..511
    const int stile = bid & 31;
    const int plane = bid >> 5;                  // b*8 + kh
    const int b = plane >> 3, kh = plane & 7;
    const int s0 = stile * 64;
    const int t = threadIdx.x;
    const int r = t >> 2, u0 = t & 3;

    const u16* src = qkv + ((size_t)(b * S_LEN + s0 + r)) * EQKV + (HQ + HKV + kh) * HD;
    *(uint4*)&T[r][u0 * 8]      = *(const uint4*)(src + u0 * 8);
    *(uint4*)&T[r][u0 * 8 + 32] = *(const uint4*)(src + u0 * 8 + 32);
    __syncthreads();

    const int d = t >> 2;
    u16* dst = VTb + ((size_t)plane * HD + d) * S_LEN + s0;
#pragma unroll
    for (int half = 0; half < 2; ++half) {
      int ub = u0 + half * 4;
      u16 tmp[8];
#pragma unroll
      for (int j = 0; j < 8; ++j) tmp[j] = T[ub * 8 + j][d];
      *(uint4*)(dst + ub * 8) = *(const uint4*)tmp;
    }
  }
}

// ---------------- MFMA causal GQA flash attention, GQA sharing + CU balance ----------------
// 256 threads = 4 waves; one block = TWO heads of the same KV group at the SAME
// tile (wave wv: head 4kh+2hp+(wv>>1), rows (wv&1)*32..). All 4 waves share one
// K/V staging stream. Single-buffer LDS 16KB (dbuf measured neutral).
// CU-balanced y->tile map: blocks land on CUs in ID-stride-256 sets {y0,y0+8,
// y0+16,y0+24}; map {y0, 15-y0, 16+y0, 31-y0} makes every CU's resident tile
// sum = 62 -> per-CU iters uniform at 66 (was 52..80, 18% imbalance).
// Fixed-max softmax: ||q||=||k||=8 => |s|<=8.06; P = 2^s (scale-invariant),
// Q pre-scaled by log2e/8 in prep; l via ones-A MFMA.
__global__ __launch_bounds__(256) void attn_mfma(const u16* __restrict__ Qb,
                                                 const u16* __restrict__ Kb,
                                                 const u16* __restrict__ VTb,
                                                 u16* __restrict__ Ob) {
  __shared__ u16 Ks[64 * 64];  // [kv][128B], unit u holds global d-unit u^(kv&7)
  __shared__ u16 Vt[64 * 64];  // [d][128B],  unit u holds global kv-unit u^(d&7)
  const int tid  = threadIdx.x;
  const int wv   = tid >> 6;              // 0..3
  const int lane = tid & 63;
  const int fr   = lane & 15;
  const int fq   = lane >> 4;
  const int bx   = blockIdx.x;            // b*16 + kh*2 + hp
  const int b    = bx >> 4;
  const int kh   = (bx >> 1) & 7;
  const int hp   = bx & 1;
  const int head = kh * 4 + hp * 2 + (wv >> 1);
  const int bh   = b * 32 + head;
  const size_t kvbase = ((size_t)(b * HKV + kh)) * S_LEN * HD;

  // CU-balanced tile map (bijective over 0..31; each stride-8 class sums to 62)
  const int y0 = (int)blockIdx.y & 7, yj = (int)blockIdx.y >> 3;
  const int tile = (yj == 0) ? y0 : (yj == 1) ? 15 - y0 : (yj == 2) ? 16 + y0 : 31 - y0;
  const int wqmin  = tile * 64 + (wv & 1) * 32;
  const int kv_end = tile * 64 + 64;

  const int srow  = lane >> 3;                 // row within 8-row chunk
  const int sunit = (lane & 7) ^ srow;         // pre-swizzled global 16B unit
  const u16* kp0 = Kb  + kvbase + (size_t)(wv * 16 + srow) * HD    + sunit * 8;
  const u16* vp0 = VTb + kvbase + (size_t)(wv * 16 + srow) * S_LEN + sunit * 8;

  bf16x8 aq[2][2];   // Q pre-scaled by log2e/8 in prep — raw loads
#pragma unroll
  for (int qf = 0; qf < 2; ++qf)
#pragma unroll
    for (int kc = 0; kc < 2; ++kc)
      aq[qf][kc] = *(const bf16x8*)(Qb + ((size_t)bh * S_LEN + (wqmin + qf * 16 + fr)) * HD + kc * 32 + fq * 8);

  const f32x4 Z4 = (f32x4){0.f, 0.f, 0.f, 0.f};
  bf16x4 ones;
#pragma unroll
  for (int v = 0; v < 4; ++v) ones[v] = (short)0x3F80;   // bf16 1.0

  f32x4 o[2][4];
#pragma unroll
  for (int qf = 0; qf < 2; ++qf)
#pragma unroll
    for (int df = 0; df < 4; ++df) o[qf][df] = Z4;
  f32x4 lacc[2] = {Z4, Z4};

  for (int k0 = 0; k0 < kv_end; k0 += 64) {
    __syncthreads();
    // ---- stage K + V^T tiles: 16 chunks over 4 waves (2 K + 2 V each) ----
#pragma unroll
    for (int i = 0; i < 2; ++i) {
      gld16(kp0 + (size_t)(k0 + i * 8) * HD,    (char*)Ks + (wv * 2 + i) * 1024);
      gld16(vp0 + k0 + (size_t)(i * 8) * S_LEN, (char*)Vt + (wv * 2 + i) * 1024);
    }
    __syncthreads();

    // ---- QK^T (swapped): st[qf][kf], col=q=fr, row=kv=fq*4+v ----
    f32x4 st[2][4];
    __builtin_amdgcn_s_setprio(1);
#pragma unroll
    for (int kf = 0; kf < 4; ++kf) {
      int row = kf * 16 + fr;
      bf16x8 ak0 = *(const bf16x8*)((char*)Ks + row * 128 +
                                    ((fq * 16) ^ ((row & 7) << 4)));
      bf16x8 ak1 = *(const bf16x8*)((char*)Ks + row * 128 +
                                    ((64 + fq * 16) ^ ((row & 7) << 4)));
#pragma unroll
      for (int qf = 0; qf < 2; ++qf) {
        f32x4 tt = __builtin_amdgcn_mfma_f32_16x16x32_bf16(ak0, aq[qf][0], Z4, 0, 0, 0);
        st[qf][kf] = __builtin_amdgcn_mfma_f32_16x16x32_bf16(ak1, aq[qf][1], tt, 0, 0, 0);
      }
    }
    __builtin_amdgcn_s_setprio(0);

    // ---- softmax numerator: P = 2^st (masked -> 0) ----
    const bool need_mask = (k0 + 63 > wqmin);
    bf16x4 pb[2][4];
#pragma unroll
    for (int qf = 0; qf < 2; ++qf) {
      const int qrow = wqmin + qf * 16 + fr;
      if (need_mask) {
#pragma unroll
        for (int kf = 0; kf < 4; ++kf)
#pragma unroll
          for (int v = 0; v < 4; ++v) {
            int kvg = k0 + kf * 16 + fq * 4 + v;
            st[qf][kf][v] = (kvg > qrow) ? -1e30f : st[qf][kf][v];
          }
      }
#pragma unroll
      for (int kf = 0; kf < 4; ++kf) {
        bf16x4 pp;
#pragma unroll
        for (int v = 0; v < 4; ++v) pp[v] = f2bf_s(fexp2(st[qf][kf][v]));
        pb[qf][kf] = pp;
      }
    }

    // ---- PV: O^T += V^T * P^T ; l += rowsum(P) via ones-A MFMA ----
    __builtin_amdgcn_s_setprio(1);
#pragma unroll
    for (int df = 0; df < 4; ++df) {
      int row = df * 16 + fr;
#pragma unroll
      for (int kf = 0; kf < 4; ++kf) {
        bf16x4 av = *(const bf16x4*)((char*)Vt + row * 128 +
                                     ((kf * 32 + fq * 8) ^ ((row & 7) << 4)));
#pragma unroll
        for (int qf = 0; qf < 2; ++qf)
          o[qf][df] = __builtin_amdgcn_mfma_f32_16x16x16bf16_1k(av, pb[qf][kf], o[qf][df], 0, 0, 0);
      }
    }
#pragma unroll
    for (int kf = 0; kf < 4; ++kf)
#pragma unroll
      for (int qf = 0; qf < 2; ++qf)
        lacc[qf] = __builtin_amdgcn_mfma_f32_16x16x16bf16_1k(ones, pb[qf][kf], lacc[qf], 0, 0, 0);
    __builtin_amdgcn_s_setprio(0);
  }

  // ---- write O (O^T layout: col=q=fr lane-local; l lane-local from MFMA) ----
#pragma unroll
  for (int qf = 0; qf < 2; ++qf) {
    float inv = 1.0f / lacc[qf][0];
    int grow = b * S_LEN + wqmin + qf * 16 + fr;
#pragma unroll
    for (int df = 0; df < 4; ++df) {
      u16* op = Ob + (size_t)grow * DMODEL + head * HD + df * 16 + fq * 4;
      uint32_t w0 = (uint32_t)f2bf(o[qf][df][0] * inv) | ((uint32_t)f2bf(o[qf][df][1] * inv) << 16);
      uint32_t w1 = (uint32_t)f2bf(o[qf][df][2] * inv) | ((uint32_t)f2bf(o[qf][df][3] * inv) << 16);
      *(uint2*)op = make_uint2(w0, w1);
    }
  }
}

extern "C" void kernel_launch(void* const* d_in, const int* in_sizes, int n_in,
                              void* d_out, int out_size, void* d_ws, size_t ws_size,
                              hipStream_t stream) {
  const float* x    = (const float*)d_in[0];
  const float* wqkv = (const float*)d_in[1];
  const float* wout = (const float*)d_in[2];
  const float* qg   = (const float*)d_in[3];
  const float* kg   = (const float*)d_in[4];
  float* out = (float*)d_out;
  char* ws = (char*)d_ws;

  const size_t MB = 1024 * 1024;
  u16* xb    = (u16*)(ws + 0 * MB);    // 16 MB (reused as Ob)
  u16* wqkvb = (u16*)(ws + 16 * MB);   // 12 MB
  u16* qkvb  = (u16*)(ws + 28 * MB);   // 24 MB
  u16* Qb    = (u16*)(ws + 52 * MB);   // 16 MB
  u16* Kb    = (u16*)(ws + 68 * MB);   // 4 MB
  u16* VTb   = (u16*)(ws + 72 * MB);   // 4 MB
  u16* Ob    = xb;
  u16* woutb = (u16*)(ws + 76 * MB);   // 8 MB

  cast3<<<CAST_BLOCKS, 256, 0, stream>>>(x, wqkv, wout, xb, wqkvb, woutb);
  gemm_bt<1><<<(MROWS / 128) * (EQKV / 128), 512, 0, stream>>>(xb, wqkvb, qkvb, MROWS, EQKV, DMODEL, MROWS / 128);
  prep<<<RMS_BLOCKS + BATCH * HKV * 32, 256, 0, stream>>>(qkvb, Qb, Kb, VTb, qg, kg);
  attn_mfma<<<dim3(32, 32), 256, 0, stream>>>(Qb, Kb, VTb, Ob);
  gemm_bt<0><<<(MROWS / 128) * (DMODEL / 128), 512, 0, stream>>>(Ob, woutb, out, MROWS, DMODEL, DMODEL, MROWS / 128);
}

// Round 17
// 196.244 us; speedup vs baseline: 1.0470x; 1.0470x over previous
//
#include <hip/hip_runtime.h>
#include <hip/hip_bf16.h>
#include <stdint.h>

#define S_LEN  2048
#define BATCH  2
#define DMODEL 2048
#define EQKV   3072
#define HQ     32
#define HKV    8
#define HD     64
#define MROWS  (BATCH * S_LEN)  // 4096

typedef unsigned short u16;
typedef __attribute__((ext_vector_type(8))) short bf16x8;
typedef __attribute__((ext_vector_type(4))) short bf16x4;
typedef __attribute__((ext_vector_type(4))) float f32x4;

__device__ __forceinline__ u16 f2bf(float f) {
  uint32_t x = __builtin_bit_cast(uint32_t, f);
  uint32_t r = x + 0x7fffu + ((x >> 16) & 1u);
  return (u16)(r >> 16);
}
__device__ __forceinline__ short f2bf_s(float f) {
  return __builtin_bit_cast(short, __float2bfloat16(f));
}
__device__ __forceinline__ float b2f(u16 u) {
  uint32_t x = ((uint32_t)u) << 16;
  return __builtin_bit_cast(float, x);
}
__device__ __forceinline__ float fexp2(float x) {
#if __has_builtin(__builtin_amdgcn_exp2f)
  return __builtin_amdgcn_exp2f(x);
#else
  return exp2f(x);
#endif
}

__device__ __forceinline__ void gld16(const void* g, void* l) {
  __builtin_amdgcn_global_load_lds(
      (const __attribute__((address_space(1))) void*)g,
      (__attribute__((address_space(3))) void*)l, 16, 0, 0);
}

// ---------------- cast fp32 -> bf16, region-split (uniform branch per block) ----------------
// blocks [0,2048): x; [2048,3584): w_qkv; [3584,4608): w_out.
// One thread = 2 consecutive 8-elem units (64B read, 32B write), no loop.
#define CAST_BLOCKS 4608
__global__ __launch_bounds__(256) void cast3(const float* __restrict__ xa, const float* __restrict__ xb,
                      const float* __restrict__ xc,
                      u16* __restrict__ oa, u16* __restrict__ ob, u16* __restrict__ oc) {
  const float* in;
  u16* out;
  int bid = blockIdx.x;
  if (bid < 2048)      { in = xa; out = oa; }
  else if (bid < 3584) { in = xb; out = ob; bid -= 2048; }
  else                 { in = xc; out = oc; bid -= 3584; }
  size_t u0 = ((size_t)bid * 256 + threadIdx.x) * 2;   // unit index (8 elems/unit)
#pragma unroll
  for (int k = 0; k < 2; ++k) {
    size_t j = u0 + k;
    const float4* p = (const float4*)(in + j * 8);
    float4 a = p[0], b = p[1];
    uint32_t w0 = (uint32_t)(u16)f2bf_s(a.x) | ((uint32_t)(u16)f2bf_s(a.y) << 16);
    uint32_t w1 = (uint32_t)(u16)f2bf_s(a.z) | ((uint32_t)(u16)f2bf_s(a.w) << 16);
    uint32_t w2 = (uint32_t)(u16)f2bf_s(b.x) | ((uint32_t)(u16)f2bf_s(b.y) << 16);
    uint32_t w3 = (uint32_t)(u16)f2bf_s(b.z) | ((uint32_t)(u16)f2bf_s(b.w) << 16);
    *(uint4*)(out + j * 8) = make_uint4(w0, w1, w2, w3);
  }
}

// ---------------- bf16 GEMM, C = A * B^T ----------------
// 128x128 tile, BK=64, 8 waves (2 row-halves x 4 col-quarters; 64x32 per wave).
// LDS [128 rows][8 x 16B units]; unit u of row r holds global k-unit u^(r&7),
// staged via global_load_lds (linear dest) with pre-swizzled SOURCE unit.
template<int OUT_BF16>
__global__ __launch_bounds__(512) void gemm_bt(const u16* __restrict__ A,
                                               const u16* __restrict__ Bm,
                                               void* __restrict__ Cv,
                                               int M, int N, int K, int nbx) {
  __shared__ u16 lA[128 * 64];
  __shared__ u16 lB[128 * 64];
  const int tid  = threadIdx.x;
  const int wave = tid >> 6;
  const int lane = tid & 63;

  const int nwg = gridDim.x;
  const int wg  = blockIdx.x;
  const int swz = (wg & 7) * (nwg >> 3) + (wg >> 3);
  const int brow = (swz % nbx) * 128;
  const int bcol = (swz / nbx) * 128;

  const int wr = (wave >> 2) * 64;   // row half
  const int wc = (wave & 3) * 32;    // col quarter
  const int fr = lane & 15;
  const int fq = lane >> 4;

  const int srow8 = lane >> 3;                    // row within 8-row chunk
  const int scol  = ((lane & 7) ^ srow8) * 8;     // pre-swizzled source k-unit

  f32x4 acc[4][2];
#pragma unroll
  for (int i = 0; i < 4; ++i)
#pragma unroll
    for (int j = 0; j < 2; ++j) acc[i][j] = (f32x4){0.f, 0.f, 0.f, 0.f};

  for (int k0 = 0; k0 < K; k0 += 64) {
    __syncthreads();
#pragma unroll
    for (int j = 0; j < 2; ++j) {
      int c = wave * 2 + j;                 // chunk id 0..15
      int r = c * 8 + srow8;
      gld16(A  + (size_t)(brow + r) * K + k0 + scol, (char*)lA + c * 1024);
      gld16(Bm + (size_t)(bcol + r) * K + k0 + scol, (char*)lB + c * 1024);
    }
    __syncthreads();

    bf16x8 af[2][4], bfr[2][2];
#pragma unroll
    for (int kc = 0; kc < 2; ++kc) {
#pragma unroll
      for (int i = 0; i < 4; ++i) {
        int row = wr + i * 16 + fr;
        af[kc][i] = *(const bf16x8*)&lA[row * 64 + (((kc * 4 + fq) ^ (row & 7)) << 3)];
      }
#pragma unroll
      for (int j = 0; j < 2; ++j) {
        int row = wc + j * 16 + fr;
        bfr[kc][j] = *(const bf16x8*)&lB[row * 64 + (((kc * 4 + fq) ^ (row & 7)) << 3)];
      }
    }
#pragma unroll
    for (int kc = 0; kc < 2; ++kc)
#pragma unroll
      for (int i = 0; i < 4; ++i)
#pragma unroll
        for (int j = 0; j < 2; ++j)
          acc[i][j] = __builtin_amdgcn_mfma_f32_16x16x32_bf16(af[kc][i], bfr[kc][j], acc[i][j], 0, 0, 0);
  }

#pragma unroll
  for (int i = 0; i < 4; ++i)
#pragma unroll
    for (int j = 0; j < 2; ++j)
#pragma unroll
      for (int v = 0; v < 4; ++v) {
        int row = brow + wr + i * 16 + fq * 4 + v;
        int col = bcol + wc + j * 16 + fr;
        float val = acc[i][j][v];
        if (OUT_BF16) ((u16*)Cv)[(size_t)row * N + col] = f2bf(val);
        else          ((float*)Cv)[(size_t)row * N + col] = val;
      }
}

// ---------------- fused prep: RMSNorm+RoPE (Q/K) and V transpose ----------------
// blocks [0, 40960): rmsrope — one wave per (b,s,head<40) row of 64.
//   Q rows additionally pre-scaled by log2(e)/8 (attn's fixed-max softmax scale).
//   Trig via revolution-space reduction + native __sinf/__cosf.
// blocks [40960, 41472): vtrans — V heads -> VT [b*8+kh][d=64][S=2048].
#define RMS_BLOCKS 40960
__global__ __launch_bounds__(256) void prep(const u16* __restrict__ qkv,
                                            u16* __restrict__ Qb,
                                            u16* __restrict__ Kb,
                                            u16* __restrict__ VTb,
                                            const float* __restrict__ qg,
                                            const float* __restrict__ kg) {
  __shared__ u16 T[64][68];
  if (blockIdx.x < RMS_BLOCKS) {
    int wid  = blockIdx.x * 4 + (threadIdx.x >> 6);
    int lane = threadIdx.x & 63;
    int head = wid % 40;
    int bs   = wid / 40;
    int s    = bs & (S_LEN - 1);
    int b    = bs >> 11;

    float v = b2f(qkv[(size_t)bs * EQKV + head * HD + lane]);
    float ss = v * v;
#pragma unroll
    for (int msk = 32; msk >= 1; msk >>= 1) ss += __shfl_xor(ss, msk);
    float norm = sqrtf(ss);
    float g = (head < 32) ? qg[lane] : kg[lane];
    float xv = v * (8.0f * g / fmaxf(norm, 1e-6f));
    float prt = __shfl_xor(xv, 32);
    int i = lane & 31;
    // freq in revolutions: exp(-i*ln(1e4)/32) / (2*pi)
    float freq_rev = __expf(-(float)i * 0.28782313662425572f) * 0.15915494309189535f;
    float tr = (float)s * freq_rev;
    tr -= floorf(tr);
    float ang = tr * 6.283185307179586f;
    float sn = __sinf(ang), cs = __cosf(ang);
    float res = (lane < 32) ? (xv * cs - prt * sn) : (prt * sn + xv * cs);
    if (head < 32) {
      res *= 0.18033688011112042f;   // fold log2(e)/8 into stored Q
      Qb[(((size_t)(b * HQ  + head     )) * S_LEN + s) * HD + lane] = f2bf(res);
    } else {
      Kb[(((size_t)(b * HKV + head - 32)) * S_LEN + s) * HD + lane] = f2bf(res);
    }
  } else {
    const int bid   = blockIdx.x - RMS_BLOCKS;   // 0..511
    const int stile = bid & 31;
    const int plane = bid >> 5;                  // b*8 + kh
    const int b = plane >> 3, kh = plane & 7;
    const int s0 = stile * 64;
    const int t = threadIdx.x;
    const int r = t >> 2, u0 = t & 3;

    const u16* src = qkv + ((size_t)(b * S_LEN + s0 + r)) * EQKV + (HQ + HKV + kh) * HD;
    *(uint4*)&T[r][u0 * 8]      = *(const uint4*)(src + u0 * 8);
    *(uint4*)&T[r][u0 * 8 + 32] = *(const uint4*)(src + u0 * 8 + 32);
    __syncthreads();

    const int d = t >> 2;
    u16* dst = VTb + ((size_t)plane * HD + d) * S_LEN + s0;
#pragma unroll
    for (int half = 0; half < 2; ++half) {
      int ub = u0 + half * 4;
      u16 tmp[8];
#pragma unroll
      for (int j = 0; j < 8; ++j) tmp[j] = T[ub * 8 + j][d];
      *(uint4*)(dst + ub * 8) = *(const uint4*)tmp;
    }
  }
}

// ---------------- MFMA causal GQA flash attention, GQA head-sharing (r15 best) ----------------
// 256 threads = 4 waves; one block = TWO heads of the same KV group at the SAME
// tile (wave wv: head 4kh+2hp+(wv>>1), rows (wv&1)*32..). All 4 waves share one
// K/V staging stream (2+2 gld16 chunks per wave) with identical kv ranges and
// mask timing. Single-buffer LDS 16KB — dbuf measured neutral (r14), TLP at
// 4-5 blocks/CU already hides staging latency. tile=31-y heavy-first ordering
// (r16's "balanced" remap measured -18%: trust the scheduler's natural packing).
// Fixed-max softmax: ||q||=||k||=8 => |s|<=8.06; P = 2^s (scale-invariant),
// Q pre-scaled by log2e/8 in prep; l via ones-A MFMA.
__global__ __launch_bounds__(256) void attn_mfma(const u16* __restrict__ Qb,
                                                 const u16* __restrict__ Kb,
                                                 const u16* __restrict__ VTb,
                                                 u16* __restrict__ Ob) {
  __shared__ u16 Ks[64 * 64];  // [kv][128B], unit u holds global d-unit u^(kv&7)
  __shared__ u16 Vt[64 * 64];  // [d][128B],  unit u holds global kv-unit u^(d&7)
  const int tid  = threadIdx.x;
  const int wv   = tid >> 6;              // 0..3
  const int lane = tid & 63;
  const int fr   = lane & 15;
  const int fq   = lane >> 4;
  const int bx   = blockIdx.x;            // b*16 + kh*2 + hp
  const int b    = bx >> 4;
  const int kh   = (bx >> 1) & 7;
  const int hp   = bx & 1;
  const int head = kh * 4 + hp * 2 + (wv >> 1);
  const int bh   = b * 32 + head;
  const size_t kvbase = ((size_t)(b * HKV + kh)) * S_LEN * HD;

  const int tile   = 31 - (int)blockIdx.y;   // heavy tiles dispatch first
  const int wqmin  = tile * 64 + (wv & 1) * 32;
  const int kv_end = tile * 64 + 64;

  const int srow  = lane >> 3;                 // row within 8-row chunk
  const int sunit = (lane & 7) ^ srow;         // pre-swizzled global 16B unit
  const u16* kp0 = Kb  + kvbase + (size_t)(wv * 16 + srow) * HD    + sunit * 8;
  const u16* vp0 = VTb + kvbase + (size_t)(wv * 16 + srow) * S_LEN + sunit * 8;

  bf16x8 aq[2][2];   // Q pre-scaled by log2e/8 in prep — raw loads
#pragma unroll
  for (int qf = 0; qf < 2; ++qf)
#pragma unroll
    for (int kc = 0; kc < 2; ++kc)
      aq[qf][kc] = *(const bf16x8*)(Qb + ((size_t)bh * S_LEN + (wqmin + qf * 16 + fr)) * HD + kc * 32 + fq * 8);

  const f32x4 Z4 = (f32x4){0.f, 0.f, 0.f, 0.f};
  bf16x4 ones;
#pragma unroll
  for (int v = 0; v < 4; ++v) ones[v] = (short)0x3F80;   // bf16 1.0

  f32x4 o[2][4];
#pragma unroll
  for (int qf = 0; qf < 2; ++qf)
#pragma unroll
    for (int df = 0; df < 4; ++df) o[qf][df] = Z4;
  f32x4 lacc[2] = {Z4, Z4};

  for (int k0 = 0; k0 < kv_end; k0 += 64) {
    __syncthreads();
    // ---- stage K + V^T tiles: 16 chunks over 4 waves (2 K + 2 V each) ----
#pragma unroll
    for (int i = 0; i < 2; ++i) {
      gld16(kp0 + (size_t)(k0 + i * 8) * HD,    (char*)Ks + (wv * 2 + i) * 1024);
      gld16(vp0 + k0 + (size_t)(i * 8) * S_LEN, (char*)Vt + (wv * 2 + i) * 1024);
    }
    __syncthreads();

    // ---- QK^T (swapped): st[qf][kf], col=q=fr, row=kv=fq*4+v ----
    f32x4 st[2][4];
    __builtin_amdgcn_s_setprio(1);
#pragma unroll
    for (int kf = 0; kf < 4; ++kf) {
      int row = kf * 16 + fr;
      bf16x8 ak0 = *(const bf16x8*)((char*)Ks + row * 128 +
                                    ((fq * 16) ^ ((row & 7) << 4)));
      bf16x8 ak1 = *(const bf16x8*)((char*)Ks + row * 128 +
                                    ((64 + fq * 16) ^ ((row & 7) << 4)));
#pragma unroll
      for (int qf = 0; qf < 2; ++qf) {
        f32x4 tt = __builtin_amdgcn_mfma_f32_16x16x32_bf16(ak0, aq[qf][0], Z4, 0, 0, 0);
        st[qf][kf] = __builtin_amdgcn_mfma_f32_16x16x32_bf16(ak1, aq[qf][1], tt, 0, 0, 0);
      }
    }
    __builtin_amdgcn_s_setprio(0);

    // ---- softmax numerator: P = 2^st (masked -> 0) ----
    const bool need_mask = (k0 + 63 > wqmin);
    bf16x4 pb[2][4];
#pragma unroll
    for (int qf = 0; qf < 2; ++qf) {
      const int qrow = wqmin + qf * 16 + fr;
      if (need_mask) {
#pragma unroll
        for (int kf = 0; kf < 4; ++kf)
#pragma unroll
          for (int v = 0; v < 4; ++v) {
            int kvg = k0 + kf * 16 + fq * 4 + v;
            st[qf][kf][v] = (kvg > qrow) ? -1e30f : st[qf][kf][v];
          }
      }
#pragma unroll
      for (int kf = 0; kf < 4; ++kf) {
        bf16x4 pp;
#pragma unroll
        for (int v = 0; v < 4; ++v) pp[v] = f2bf_s(fexp2(st[qf][kf][v]));
        pb[qf][kf] = pp;
      }
    }

    // ---- PV: O^T += V^T * P^T ; l += rowsum(P) via ones-A MFMA ----
    __builtin_amdgcn_s_setprio(1);
#pragma unroll
    for (int df = 0; df < 4; ++df) {
      int row = df * 16 + fr;
#pragma unroll
      for (int kf = 0; kf < 4; ++kf) {
        bf16x4 av = *(const bf16x4*)((char*)Vt + row * 128 +
                                     ((kf * 32 + fq * 8) ^ ((row & 7) << 4)));
#pragma unroll
        for (int qf = 0; qf < 2; ++qf)
          o[qf][df] = __builtin_amdgcn_mfma_f32_16x16x16bf16_1k(av, pb[qf][kf], o[qf][df], 0, 0, 0);
      }
    }
#pragma unroll
    for (int kf = 0; kf < 4; ++kf)
#pragma unroll
      for (int qf = 0; qf < 2; ++qf)
        lacc[qf] = __builtin_amdgcn_mfma_f32_16x16x16bf16_1k(ones, pb[qf][kf], lacc[qf], 0, 0, 0);
    __builtin_amdgcn_s_setprio(0);
  }

  // ---- write O (O^T layout: col=q=fr lane-local; l lane-local from MFMA) ----
#pragma unroll
  for (int qf = 0; qf < 2; ++qf) {
    float inv = 1.0f / lacc[qf][0];
    int grow = b * S_LEN + wqmin + qf * 16 + fr;
#pragma unroll
    for (int df = 0; df < 4; ++df) {
      u16* op = Ob + (size_t)grow * DMODEL + head * HD + df * 16 + fq * 4;
      uint32_t w0 = (uint32_t)f2bf(o[qf][df][0] * inv) | ((uint32_t)f2bf(o[qf][df][1] * inv) << 16);
      uint32_t w1 = (uint32_t)f2bf(o[qf][df][2] * inv) | ((uint32_t)f2bf(o[qf][df][3] * inv) << 16);
      *(uint2*)op = make_uint2(w0, w1);
    }
  }
}

extern "C" void kernel_launch(void* const* d_in, const int* in_sizes, int n_in,
                              void* d_out, int out_size, void* d_ws, size_t ws_size,
                              hipStream_t stream) {
  const float* x    = (const float*)d_in[0];
  const float* wqkv = (const float*)d_in[1];
  const float* wout = (const float*)d_in[2];
  const float* qg   = (const float*)d_in[3];
  const float* kg   = (const float*)d_in[4];
  float* out = (float*)d_out;
  char* ws = (char*)d_ws;

  const size_t MB = 1024 * 1024;
  u16* xb    = (u16*)(ws + 0 * MB);    // 16 MB (reused as Ob)
  u16* wqkvb = (u16*)(ws + 16 * MB);   // 12 MB
  u16* qkvb  = (u16*)(ws + 28 * MB);   // 24 MB
  u16* Qb    = (u16*)(ws + 52 * MB);   // 16 MB
  u16* Kb    = (u16*)(ws + 68 * MB);   // 4 MB
  u16* VTb   = (u16*)(ws + 72 * MB);   // 4 MB
  u16* Ob    = xb;
  u16* woutb = (u16*)(ws + 76 * MB);   // 8 MB

  cast3<<<CAST_BLOCKS, 256, 0, stream>>>(x, wqkv, wout, xb, wqkvb, woutb);
  gemm_bt<1><<<(MROWS / 128) * (EQKV / 128), 512, 0, stream>>>(xb, wqkvb, qkvb, MROWS, EQKV, DMODEL, MROWS / 128);
  prep<<<RMS_BLOCKS + BATCH * HKV * 32, 256, 0, stream>>>(qkvb, Qb, Kb, VTb, qg, kg);
  attn_mfma<<<dim3(32, 32), 256, 0, stream>>>(Qb, Kb, VTb, Ob);
  gemm_bt<0><<<(MROWS / 128) * (DMODEL / 128), 512, 0, stream>>>(Ob, woutb, out, MROWS, DMODEL, DMODEL, MROWS / 128);
}